// Round 3
// baseline (716.889 us; speedup 1.0000x reference)
//
#include <hip/hip_runtime.h>

typedef _Float16 half8 __attribute__((ext_vector_type(8)));
typedef _Float16 half4 __attribute__((ext_vector_type(4)));
typedef float f32x4 __attribute__((ext_vector_type(4)));

__device__ __forceinline__ void lds_load16(const void* g, void* l) {
  __builtin_amdgcn_global_load_lds((const __attribute__((address_space(1))) void*)g,
                                   (__attribute__((address_space(3))) void*)l, 16, 0, 0);
}

// ---------------- convert X f32 -> fp16 ----------------
__global__ __launch_bounds__(256) void cvt_x(const float* __restrict__ in,
                                             _Float16* __restrict__ out) {
  int i = blockIdx.x * 256 + threadIdx.x;      // one thread = 8 elements
  const float4* p = (const float4*)(in + (size_t)i * 8);
  float4 a = p[0], b = p[1];
  half8 v;
  v[0] = (_Float16)a.x; v[1] = (_Float16)a.y; v[2] = (_Float16)a.z; v[3] = (_Float16)a.w;
  v[4] = (_Float16)b.x; v[5] = (_Float16)b.y; v[6] = (_Float16)b.z; v[7] = (_Float16)b.w;
  *(half8*)(out + (size_t)i * 8) = v;
}

// ------- convert + transpose weights: Wt[n][k] = W[k][n], fp16 -------
__global__ __launch_bounds__(256) void cvt_w(const float* __restrict__ Wq, const float* __restrict__ Wk,
                                             const float* __restrict__ Wv, const float* __restrict__ Wo,
                                             _Float16* __restrict__ Wqkvt, _Float16* __restrict__ Wot) {
  int id = blockIdx.x * 256 + threadIdx.x;     // 0 .. 4*589824-1
  int part = id / 589824;
  int r = id - part * 589824;
  int k = r / 768;
  int n = r - k * 768;
  const float* W = part == 0 ? Wq : part == 1 ? Wk : part == 2 ? Wv : Wo;
  _Float16 v = (_Float16)W[(size_t)k * 768 + n];   // coalesced read over n
  if (part < 3) Wqkvt[((size_t)(part * 768 + n)) * 768 + k] = v;
  else          Wot[(size_t)n * 768 + k] = v;
}

// ---------------- fp16 MFMA GEMM, 128x128 tile, BK=32 ----------------
template <int EPI>
__global__ __launch_bounds__(256) void gemm_f16(
    const _Float16* __restrict__ A, const _Float16* __restrict__ Bt,
    const float* __restrict__ b0, const float* __restrict__ b1, const float* __restrict__ b2,
    _Float16* __restrict__ Qo, _Float16* __restrict__ Ko, _Float16* __restrict__ Vto,
    float* __restrict__ Co) {
  const int K = 768;
  __shared__ _Float16 As[128 * 32];
  __shared__ _Float16 Bs[128 * 32];
  const int tid = threadIdx.x, w = tid >> 6, l = tid & 63;
  const int lr = l & 15, lk = l >> 4;
  const int m0 = blockIdx.y * 128, n0 = blockIdx.x * 128;
  const int wr = w >> 1, wc = w & 1;
  f32x4 acc[4][4] = {};
  const int arow = tid >> 2;
  const int acolb = (tid & 3) * 16;

  for (int k0 = 0; k0 < K; k0 += 32) {
    __syncthreads();
#pragma unroll
    for (int c = 0; c < 2; ++c) {
      lds_load16((const char*)(A + (size_t)(m0 + c * 64 + arow) * K + k0) + acolb,
                 (char*)As + c * 4096 + w * 1024);
      lds_load16((const char*)(Bt + (size_t)(n0 + c * 64 + arow) * K + k0) + acolb,
                 (char*)Bs + c * 4096 + w * 1024);
    }
    __syncthreads();
    half8 af[4], bf[4];
#pragma unroll
    for (int mi = 0; mi < 4; ++mi) af[mi] = *(const half8*)&As[(wr * 64 + mi * 16 + lr) * 32 + lk * 8];
#pragma unroll
    for (int ni = 0; ni < 4; ++ni) bf[ni] = *(const half8*)&Bs[(wc * 64 + ni * 16 + lr) * 32 + lk * 8];
#pragma unroll
    for (int mi = 0; mi < 4; ++mi)
#pragma unroll
      for (int ni = 0; ni < 4; ++ni)
        acc[mi][ni] = __builtin_amdgcn_mfma_f32_16x16x32_f16(af[mi], bf[ni], acc[mi][ni], 0, 0, 0);
  }

#pragma unroll
  for (int mi = 0; mi < 4; ++mi) {
    const int rbase = m0 + wr * 64 + mi * 16 + lk * 4;
#pragma unroll
    for (int ni = 0; ni < 4; ++ni) {
      const int col = n0 + wc * 64 + ni * 16 + lr;
      if (EPI == 0) {
        const int part = col / 768;
        const int e = col - part * 768;
        const int h = e / 96, d = e - (e / 96) * 96;
        const float* bb = part == 0 ? b0 : part == 1 ? b1 : b2;
        const float bv = bb[e];
#pragma unroll
        for (int j = 0; j < 4; ++j) {
          const int row = rbase + j;
          const int b = row >> 10, s = row & 1023;
          const int bh = b * 8 + h;
          const float v = acc[mi][ni][j] + bv;
          if (part == 0)      Qo[((size_t)bh * 1024 + s) * 96 + d] = (_Float16)v;
          else if (part == 1) Ko[((size_t)bh * 1024 + s) * 96 + d] = (_Float16)v;
          else                Vto[((size_t)bh * 96 + d) * 1024 + s] = (_Float16)v;
        }
      } else {
        const float bv = b0[col];
#pragma unroll
        for (int j = 0; j < 4; ++j) {
          const int row = rbase + j;
          Co[(size_t)row * 768 + col] = acc[mi][ni][j] + bv;
        }
      }
    }
  }
}

// ---------------- fused attention v3: ZERO barriers ----------------
// K/V are L2-resident (47 MB FETCH measured) -> read MFMA fragments directly
// from global; no LDS staging, no __syncthreads anywhere. LDS only holds the
// wave-local P redistribution ([4][16][136] = 17 KB). Waves run fully
// independently; stores are never drained by barrier waitcnts.
__global__ __launch_bounds__(256) void attn(const _Float16* __restrict__ Q,
                                            const _Float16* __restrict__ Kk,
                                            const _Float16* __restrict__ Vt,
                                            float* __restrict__ probs,
                                            _Float16* __restrict__ ctx) {
  __shared__ _Float16 Ps[4][16][136];   // per-wave [16 q][128 k + 8 pad]
  const int tid = threadIdx.x, w = tid >> 6, l = tid & 63;
  const int lr = l & 15, lk = l >> 4;
  const int id = blockIdx.x;
  const int lid = (id & 7) * 256 + (id >> 3);   // XCD-chunked: 16 contiguous bh per XCD
  const int bh = lid >> 4, qt = lid & 15;
  const int q0 = qt * 64;
  const float SC = 0.10206207261596577f * 1.4426950408889634f;  // (1/sqrt(96)) * log2(e)

  const _Float16* kbh = Kk + (size_t)bh * 1024 * 96;
  const _Float16* vbh = Vt + (size_t)bh * 96 * 1024;

  // Q B-fragments, hoisted (lane owns q-row = q0 + w*16 + lr)
  half8 bq[3];
  {
    const _Float16* qrow = Q + ((size_t)bh * 1024 + q0 + w * 16 + lr) * 96;
#pragma unroll
    for (int kk = 0; kk < 3; ++kk) bq[kk] = *(const half8*)(qrow + kk * 32 + lk * 8);
  }

  // per-lane K/V fragment bases
  const _Float16* kbase = kbh + (size_t)lr * 96 + lk * 8;    // + c0*16*96 + kk*32
  const _Float16* vbase = vbh + (size_t)lr * 1024 + lk * 8;  // + dt*16*1024 + kt*128 + kk*32

  // -------- phase 1: row sums (no max: |s*SC| bounded, f32 exp2 safe) --------
  float lsum = 0.f;
#pragma unroll 4
  for (int c0 = 0; c0 < 64; ++c0) {
    const _Float16* kp = kbase + (size_t)c0 * (16 * 96);
    f32x4 s = {0.f, 0.f, 0.f, 0.f};
#pragma unroll
    for (int kk = 0; kk < 3; ++kk) {
      half8 kf = *(const half8*)(kp + kk * 32);
      s = __builtin_amdgcn_mfma_f32_16x16x32_f16(kf, bq[kk], s, 0, 0, 0);
    }
#pragma unroll
    for (int j = 0; j < 4; ++j) lsum += __builtin_amdgcn_exp2f(s[j] * SC);
  }
  lsum += __shfl_xor(lsum, 16);
  lsum += __shfl_xor(lsum, 32);
  const float invl = 1.f / lsum;

  // -------- phase 2: probs (dwordx4 stores, never drained) + PV --------
  f32x4 cacc[6] = {};
  float* pb = probs + ((size_t)bh << 20) + (size_t)(q0 + w * 16 + lr) * 1024 + lk * 4;
  for (int kt = 0; kt < 8; ++kt) {
#pragma unroll
    for (int ct = 0; ct < 8; ++ct) {
      const int c0 = kt * 8 + ct;
      const _Float16* kp = kbase + (size_t)c0 * (16 * 96);
      f32x4 s = {0.f, 0.f, 0.f, 0.f};
#pragma unroll
      for (int kk = 0; kk < 3; ++kk) {
        half8 kf = *(const half8*)(kp + kk * 32);
        s = __builtin_amdgcn_mfma_f32_16x16x32_f16(kf, bq[kk], s, 0, 0, 0);
      }
      float4 p4;
      half4 ph;
#pragma unroll
      for (int j = 0; j < 4; ++j) {
        const float p = __builtin_amdgcn_exp2f(s[j] * SC) * invl;
        ((float*)&p4)[j] = p;
        ph[j] = (_Float16)p;
      }
      *(float4*)(pb + c0 * 16) = p4;                      // coalesced 64B per lk-quad
      *(half4*)&Ps[w][lr][ct * 16 + lk * 4] = ph;         // wave-local redistribute
    }
    // PV: ctx[16 x 96] += P[16 x 128] @ V[128 x 96]  (wave-local, lgkm-ordered)
#pragma unroll
    for (int kk = 0; kk < 4; ++kk) {
      half8 pa = *(const half8*)&Ps[w][lr][kk * 32 + lk * 8];
#pragma unroll
      for (int dt = 0; dt < 6; ++dt) {
        half8 vb = *(const half8*)(vbase + (size_t)dt * (16 * 1024) + kt * 128 + kk * 32);
        cacc[dt] = __builtin_amdgcn_mfma_f32_16x16x32_f16(pa, vb, cacc[dt], 0, 0, 0);
      }
    }
  }

  // epilogue: lane holds ctx[q = w*16 + lk*4 + j][d = dt*16 + lr]
  const int b = bh >> 3, h = bh & 7;
#pragma unroll
  for (int dt = 0; dt < 6; ++dt)
#pragma unroll
    for (int j = 0; j < 4; ++j) {
      const int srow = q0 + w * 16 + lk * 4 + j;
      ctx[((size_t)(b * 1024 + srow)) * 768 + h * 96 + dt * 16 + lr] = (_Float16)cacc[dt][j];
    }
}

extern "C" void kernel_launch(void* const* d_in, const int* in_sizes, int n_in,
                              void* d_out, int out_size, void* d_ws, size_t ws_size,
                              hipStream_t stream) {
  (void)in_sizes; (void)n_in; (void)out_size; (void)ws_size;
  const float* X  = (const float*)d_in[0];
  const float* Wq = (const float*)d_in[1];
  const float* bq = (const float*)d_in[2];
  const float* Wk = (const float*)d_in[3];
  const float* bk = (const float*)d_in[4];
  const float* Wv = (const float*)d_in[5];
  const float* bv = (const float*)d_in[6];
  const float* Wo = (const float*)d_in[7];
  const float* bo = (const float*)d_in[8];

  char* ws = (char*)d_ws;
  _Float16* Xh    = (_Float16*)(ws + 0);          // 16384x768 fp16      (25165824 B)
  _Float16* Wqkvt = (_Float16*)(ws + 25165824);   // 2304x768 fp16       ( 3538944 B)
  _Float16* Wot   = (_Float16*)(ws + 28704768);   // 768x768 fp16        ( 1179648 B)
  _Float16* Qh    = (_Float16*)(ws + 29884416);   // [128][1024][96]     (25165824 B)
  _Float16* Kh    = (_Float16*)(ws + 55050240);   // [128][1024][96]     (25165824 B)
  _Float16* Vth   = (_Float16*)(ws + 80216064);   // [128][96][1024]     (25165824 B)
  _Float16* Ctx   = (_Float16*)(ws + 105381888);  // [16384][768]        (25165824 B)

  float* out   = (float*)d_out;
  float* probs = out + 12582912;                  // [16][8][1024][1024]

  cvt_x<<<dim3(6144), dim3(256), 0, stream>>>(X, Xh);
  cvt_w<<<dim3(9216), dim3(256), 0, stream>>>(Wq, Wk, Wv, Wo, Wqkvt, Wot);
  gemm_f16<0><<<dim3(18, 128), dim3(256), 0, stream>>>(Xh, Wqkvt, bq, bk, bv, Qh, Kh, Vth, nullptr);
  attn<<<dim3(2048), dim3(256), 0, stream>>>(Qh, Kh, Vth, probs, Ctx);
  gemm_f16<1><<<dim3(6, 128), dim3(256), 0, stream>>>(Ctx, Wot, bo, bo, bo, nullptr, nullptr, nullptr, out);
}

// Round 4
// 637.967 us; speedup vs baseline: 1.1237x; 1.1237x over previous
//
#include <hip/hip_runtime.h>

typedef _Float16 half8 __attribute__((ext_vector_type(8)));
typedef _Float16 half4 __attribute__((ext_vector_type(4)));
typedef float f32x4 __attribute__((ext_vector_type(4)));

__device__ __forceinline__ void lds_load16(const void* g, void* l) {
  __builtin_amdgcn_global_load_lds((const __attribute__((address_space(1))) void*)g,
                                   (__attribute__((address_space(3))) void*)l, 16, 0, 0);
}

// ---------------- convert X f32 -> fp16 ----------------
__global__ __launch_bounds__(256) void cvt_x(const float* __restrict__ in,
                                             _Float16* __restrict__ out) {
  int i = blockIdx.x * 256 + threadIdx.x;      // one thread = 8 elements
  const float4* p = (const float4*)(in + (size_t)i * 8);
  float4 a = p[0], b = p[1];
  half8 v;
  v[0] = (_Float16)a.x; v[1] = (_Float16)a.y; v[2] = (_Float16)a.z; v[3] = (_Float16)a.w;
  v[4] = (_Float16)b.x; v[5] = (_Float16)b.y; v[6] = (_Float16)b.z; v[7] = (_Float16)b.w;
  *(half8*)(out + (size_t)i * 8) = v;
}

// ------- convert + transpose weights: Wt[n][k] = W[k][n], fp16 -------
__global__ __launch_bounds__(256) void cvt_w(const float* __restrict__ Wq, const float* __restrict__ Wk,
                                             const float* __restrict__ Wv, const float* __restrict__ Wo,
                                             _Float16* __restrict__ Wqkvt, _Float16* __restrict__ Wot) {
  int id = blockIdx.x * 256 + threadIdx.x;     // 0 .. 4*589824-1
  int part = id / 589824;
  int r = id - part * 589824;
  int k = r / 768;
  int n = r - k * 768;
  const float* W = part == 0 ? Wq : part == 1 ? Wk : part == 2 ? Wv : Wo;
  _Float16 v = (_Float16)W[(size_t)k * 768 + n];   // coalesced read over n
  if (part < 3) Wqkvt[((size_t)(part * 768 + n)) * 768 + k] = v;
  else          Wot[(size_t)n * 768 + k] = v;
}

// ---------------- fp16 MFMA GEMM, 128x128 tile, BK=32 ----------------
template <int EPI>
__global__ __launch_bounds__(256) void gemm_f16(
    const _Float16* __restrict__ A, const _Float16* __restrict__ Bt,
    const float* __restrict__ b0, const float* __restrict__ b1, const float* __restrict__ b2,
    _Float16* __restrict__ Qo, _Float16* __restrict__ Ko, _Float16* __restrict__ Vto,
    float* __restrict__ Co) {
  const int K = 768;
  __shared__ _Float16 As[128 * 32];
  __shared__ _Float16 Bs[128 * 32];
  const int tid = threadIdx.x, w = tid >> 6, l = tid & 63;
  const int lr = l & 15, lk = l >> 4;
  const int m0 = blockIdx.y * 128, n0 = blockIdx.x * 128;
  const int wr = w >> 1, wc = w & 1;
  f32x4 acc[4][4] = {};
  const int arow = tid >> 2;
  const int acolb = (tid & 3) * 16;

  for (int k0 = 0; k0 < K; k0 += 32) {
    __syncthreads();
#pragma unroll
    for (int c = 0; c < 2; ++c) {
      lds_load16((const char*)(A + (size_t)(m0 + c * 64 + arow) * K + k0) + acolb,
                 (char*)As + c * 4096 + w * 1024);
      lds_load16((const char*)(Bt + (size_t)(n0 + c * 64 + arow) * K + k0) + acolb,
                 (char*)Bs + c * 4096 + w * 1024);
    }
    __syncthreads();
    half8 af[4], bf[4];
#pragma unroll
    for (int mi = 0; mi < 4; ++mi) af[mi] = *(const half8*)&As[(wr * 64 + mi * 16 + lr) * 32 + lk * 8];
#pragma unroll
    for (int ni = 0; ni < 4; ++ni) bf[ni] = *(const half8*)&Bs[(wc * 64 + ni * 16 + lr) * 32 + lk * 8];
#pragma unroll
    for (int mi = 0; mi < 4; ++mi)
#pragma unroll
      for (int ni = 0; ni < 4; ++ni)
        acc[mi][ni] = __builtin_amdgcn_mfma_f32_16x16x32_f16(af[mi], bf[ni], acc[mi][ni], 0, 0, 0);
  }

#pragma unroll
  for (int mi = 0; mi < 4; ++mi) {
    const int rbase = m0 + wr * 64 + mi * 16 + lk * 4;
#pragma unroll
    for (int ni = 0; ni < 4; ++ni) {
      const int col = n0 + wc * 64 + ni * 16 + lr;
      if (EPI == 0) {
        const int part = col / 768;
        const int e = col - part * 768;
        const int h = e / 96, d = e - (e / 96) * 96;
        const float* bb = part == 0 ? b0 : part == 1 ? b1 : b2;
        const float bv = bb[e];
#pragma unroll
        for (int j = 0; j < 4; ++j) {
          const int row = rbase + j;
          const int b = row >> 10, s = row & 1023;
          const int bh = b * 8 + h;
          const float v = acc[mi][ni][j] + bv;
          if (part == 0)      Qo[((size_t)bh * 1024 + s) * 96 + d] = (_Float16)v;
          else if (part == 1) Ko[((size_t)bh * 1024 + s) * 96 + d] = (_Float16)v;
          else                Vto[((size_t)bh * 96 + d) * 1024 + s] = (_Float16)v;
        }
      } else {
        const float bv = b0[col];
#pragma unroll
        for (int j = 0; j < 4; ++j) {
          const int row = rbase + j;
          Co[(size_t)row * 768 + col] = acc[mi][ni][j] + bv;
        }
      }
    }
  }
}

// ---------------- fused attention v4: single-pass, scores in registers ----------------
// Block = 4 waves = one 16-q-row tile; wave w owns k-slice [w*256, w*256+256).
// Scores S^T = mfma(K,Q): lane owns q-row lr, 64 score f32 regs for its slice.
// QK^T and exp computed ONCE. 2 barriers total (lsum reduce, ctx reduce).
__global__ __launch_bounds__(256) void attn(const _Float16* __restrict__ Q,
                                            const _Float16* __restrict__ Kk,
                                            const _Float16* __restrict__ Vt,
                                            float* __restrict__ probs,
                                            _Float16* __restrict__ ctx) {
  // per-wave 8448B region: first Ps fp16 [16][264], later ctx-partial f32 [16][100]
  __shared__ __align__(16) char lds[4][8448];
  __shared__ float lsb[4][16];
  const int tid = threadIdx.x, w = tid >> 6, l = tid & 63;
  const int lr = l & 15, lk = l >> 4;
  const int id = blockIdx.x;
  const int lid = (id & 7) * 1024 + (id >> 3);   // XCD-chunked: 16 contiguous bh per XCD
  const int bh = lid >> 6, qt = lid & 63;
  const int q0 = qt * 16;
  const float SC = 0.10206207261596577f * 1.4426950408889634f;  // (1/sqrt(96)) * log2(e)

  _Float16* Ps = (_Float16*)lds[w];   // [16][264] (+8 pad)
  float* cbw = (float*)lds[w];        // [16][100] (reused after PV)

  const _Float16* kbh = Kk + (size_t)bh * 1024 * 96;
  const _Float16* vbh = Vt + (size_t)bh * 96 * 1024;

  // Q B-fragments (all waves load the same 16 q-rows)
  half8 bq[3];
  {
    const _Float16* qrow = Q + ((size_t)bh * 1024 + q0 + lr) * 96;
#pragma unroll
    for (int kk = 0; kk < 3; ++kk) bq[kk] = *(const half8*)(qrow + kk * 32 + lk * 8);
  }

  // ---- scores for the whole 256-k slice, in registers ----
  f32x4 s[16];
  const _Float16* kb = kbh + (size_t)(w * 256 + lr) * 96 + lk * 8;
#pragma unroll
  for (int ct = 0; ct < 16; ++ct) {
    f32x4 acc = {0.f, 0.f, 0.f, 0.f};
#pragma unroll
    for (int kk = 0; kk < 3; ++kk) {
      half8 kf = *(const half8*)(kb + (size_t)ct * (16 * 96) + kk * 32);
      acc = __builtin_amdgcn_mfma_f32_16x16x32_f16(kf, bq[kk], acc, 0, 0, 0);
    }
    s[ct] = acc;
  }

  // ---- exp (in place) + per-lane partial sum ----
  float psum = 0.f;
#pragma unroll
  for (int ct = 0; ct < 16; ++ct)
#pragma unroll
    for (int j = 0; j < 4; ++j) {
      const float e = __builtin_amdgcn_exp2f(s[ct][j] * SC);
      s[ct][j] = e;
      psum += e;
    }
  psum += __shfl_xor(psum, 16);
  psum += __shfl_xor(psum, 32);
  if (lk == 0) lsb[w][lr] = psum;
  __syncthreads();
  const float invl = 1.f / (lsb[0][lr] + lsb[1][lr] + lsb[2][lr] + lsb[3][lr]);

  // ---- normalized probs stores + P redistribute (wave-local) ----
  float* pb = probs + ((size_t)bh << 20) + (size_t)(q0 + lr) * 1024 + w * 256 + lk * 4;
#pragma unroll
  for (int ct = 0; ct < 16; ++ct) {
    float4 p4;
    half4 ph;
#pragma unroll
    for (int j = 0; j < 4; ++j) {
      const float p = s[ct][j] * invl;
      ((float*)&p4)[j] = p;
      ph[j] = (_Float16)p;
    }
    *(float4*)(pb + ct * 16) = p4;
    *(half4*)&Ps[lr * 264 + ct * 16 + lk * 4] = ph;
  }

  // ---- PV over this wave's k-slice: partial ctx[16 x 96] ----
  f32x4 cacc[6] = {};
  const _Float16* vb0 = vbh + (size_t)lr * 1024 + w * 256 + lk * 8;
#pragma unroll
  for (int kk = 0; kk < 8; ++kk) {
    half8 pa = *(const half8*)&Ps[lr * 264 + kk * 32 + lk * 8];
#pragma unroll
    for (int dt = 0; dt < 6; ++dt) {
      half8 vbf = *(const half8*)(vb0 + (size_t)dt * (16 * 1024) + kk * 32);
      cacc[dt] = __builtin_amdgcn_mfma_f32_16x16x32_f16(pa, vbf, cacc[dt], 0, 0, 0);
    }
  }

  // ---- wave-local partial -> LDS f32 (overwrites own Ps region; DS is per-wave in-order) ----
#pragma unroll
  for (int dt = 0; dt < 6; ++dt)
#pragma unroll
    for (int j = 0; j < 4; ++j)
      cbw[(lk * 4 + j) * 100 + dt * 16 + lr] = cacc[dt][j];
  __syncthreads();

  // ---- cross-wave reduce + ctx store: 1536 elems, 6 per thread ----
  const int q = tid >> 4;
  const int d0 = (tid & 15) * 6;
  const int b = bh >> 3, h = bh & 7;
  _Float16* cg = ctx + ((size_t)(b * 1024 + q0 + q)) * 768 + h * 96 + d0;
#pragma unroll
  for (int e = 0; e < 6; ++e) {
    float v = 0.f;
#pragma unroll
    for (int ww = 0; ww < 4; ++ww) v += ((const float*)lds[ww])[q * 100 + d0 + e];
    cg[e] = (_Float16)v;
  }
}

extern "C" void kernel_launch(void* const* d_in, const int* in_sizes, int n_in,
                              void* d_out, int out_size, void* d_ws, size_t ws_size,
                              hipStream_t stream) {
  (void)in_sizes; (void)n_in; (void)out_size; (void)ws_size;
  const float* X  = (const float*)d_in[0];
  const float* Wq = (const float*)d_in[1];
  const float* bq = (const float*)d_in[2];
  const float* Wk = (const float*)d_in[3];
  const float* bk = (const float*)d_in[4];
  const float* Wv = (const float*)d_in[5];
  const float* bv = (const float*)d_in[6];
  const float* Wo = (const float*)d_in[7];
  const float* bo = (const float*)d_in[8];

  char* ws = (char*)d_ws;
  _Float16* Xh    = (_Float16*)(ws + 0);          // 16384x768 fp16      (25165824 B)
  _Float16* Wqkvt = (_Float16*)(ws + 25165824);   // 2304x768 fp16       ( 3538944 B)
  _Float16* Wot   = (_Float16*)(ws + 28704768);   // 768x768 fp16        ( 1179648 B)
  _Float16* Qh    = (_Float16*)(ws + 29884416);   // [128][1024][96]     (25165824 B)
  _Float16* Kh    = (_Float16*)(ws + 55050240);   // [128][1024][96]     (25165824 B)
  _Float16* Vth   = (_Float16*)(ws + 80216064);   // [128][96][1024]     (25165824 B)
  _Float16* Ctx   = (_Float16*)(ws + 105381888);  // [16384][768]        (25165824 B)

  float* out   = (float*)d_out;
  float* probs = out + 12582912;                  // [16][8][1024][1024]

  cvt_x<<<dim3(6144), dim3(256), 0, stream>>>(X, Xh);
  cvt_w<<<dim3(9216), dim3(256), 0, stream>>>(Wq, Wk, Wv, Wo, Wqkvt, Wot);
  gemm_f16<0><<<dim3(18, 128), dim3(256), 0, stream>>>(Xh, Wqkvt, bq, bk, bv, Qh, Kh, Vth, nullptr);
  attn<<<dim3(8192), dim3(256), 0, stream>>>(Qh, Kh, Vth, probs, Ctx);
  gemm_f16<1><<<dim3(6, 128), dim3(256), 0, stream>>>(Ctx, Wot, bo, bo, bo, nullptr, nullptr, nullptr, out);
}

// Round 5
// 615.769 us; speedup vs baseline: 1.1642x; 1.0360x over previous
//
#include <hip/hip_runtime.h>

typedef _Float16 half8 __attribute__((ext_vector_type(8)));
typedef _Float16 half4 __attribute__((ext_vector_type(4)));
typedef float f32x4 __attribute__((ext_vector_type(4)));

__device__ __forceinline__ void lds_load16(const void* g, void* l) {
  __builtin_amdgcn_global_load_lds((const __attribute__((address_space(1))) void*)g,
                                   (__attribute__((address_space(3))) void*)l, 16, 0, 0);
}

// ---------------- convert X f32 -> fp16 ----------------
__global__ __launch_bounds__(256) void cvt_x(const float* __restrict__ in,
                                             _Float16* __restrict__ out) {
  int i = blockIdx.x * 256 + threadIdx.x;      // one thread = 8 elements
  const float4* p = (const float4*)(in + (size_t)i * 8);
  float4 a = p[0], b = p[1];
  half8 v;
  v[0] = (_Float16)a.x; v[1] = (_Float16)a.y; v[2] = (_Float16)a.z; v[3] = (_Float16)a.w;
  v[4] = (_Float16)b.x; v[5] = (_Float16)b.y; v[6] = (_Float16)b.z; v[7] = (_Float16)b.w;
  *(half8*)(out + (size_t)i * 8) = v;
}

// ------- convert + transpose weights: Wt[n][k] = W[k][n], fp16 -------
__global__ __launch_bounds__(256) void cvt_w(const float* __restrict__ Wq, const float* __restrict__ Wk,
                                             const float* __restrict__ Wv, const float* __restrict__ Wo,
                                             _Float16* __restrict__ Wqkvt, _Float16* __restrict__ Wot) {
  int id = blockIdx.x * 256 + threadIdx.x;     // 0 .. 4*589824-1
  int part = id / 589824;
  int r = id - part * 589824;
  int k = r / 768;
  int n = r - k * 768;
  const float* W = part == 0 ? Wq : part == 1 ? Wk : part == 2 ? Wv : Wo;
  _Float16 v = (_Float16)W[(size_t)k * 768 + n];   // coalesced read over n
  if (part < 3) Wqkvt[((size_t)(part * 768 + n)) * 768 + k] = v;
  else          Wot[(size_t)n * 768 + k] = v;
}

// ---------------- fp16 MFMA GEMM, 128x128 tile, BK=32 ----------------
template <int EPI>
__global__ __launch_bounds__(256) void gemm_f16(
    const _Float16* __restrict__ A, const _Float16* __restrict__ Bt,
    const float* __restrict__ b0, const float* __restrict__ b1, const float* __restrict__ b2,
    _Float16* __restrict__ Qo, _Float16* __restrict__ Ko, _Float16* __restrict__ Vto,
    float* __restrict__ Co) {
  const int K = 768;
  __shared__ _Float16 As[128 * 32];
  __shared__ _Float16 Bs[128 * 32];
  const int tid = threadIdx.x, w = tid >> 6, l = tid & 63;
  const int lr = l & 15, lk = l >> 4;
  const int m0 = blockIdx.y * 128, n0 = blockIdx.x * 128;
  const int wr = w >> 1, wc = w & 1;
  f32x4 acc[4][4] = {};
  const int arow = tid >> 2;
  const int acolb = (tid & 3) * 16;

  for (int k0 = 0; k0 < K; k0 += 32) {
    __syncthreads();
#pragma unroll
    for (int c = 0; c < 2; ++c) {
      lds_load16((const char*)(A + (size_t)(m0 + c * 64 + arow) * K + k0) + acolb,
                 (char*)As + c * 4096 + w * 1024);
      lds_load16((const char*)(Bt + (size_t)(n0 + c * 64 + arow) * K + k0) + acolb,
                 (char*)Bs + c * 4096 + w * 1024);
    }
    __syncthreads();
    half8 af[4], bf[4];
#pragma unroll
    for (int mi = 0; mi < 4; ++mi) af[mi] = *(const half8*)&As[(wr * 64 + mi * 16 + lr) * 32 + lk * 8];
#pragma unroll
    for (int ni = 0; ni < 4; ++ni) bf[ni] = *(const half8*)&Bs[(wc * 64 + ni * 16 + lr) * 32 + lk * 8];
#pragma unroll
    for (int mi = 0; mi < 4; ++mi)
#pragma unroll
      for (int ni = 0; ni < 4; ++ni)
        acc[mi][ni] = __builtin_amdgcn_mfma_f32_16x16x32_f16(af[mi], bf[ni], acc[mi][ni], 0, 0, 0);
  }

#pragma unroll
  for (int mi = 0; mi < 4; ++mi) {
    const int rbase = m0 + wr * 64 + mi * 16 + lk * 4;
#pragma unroll
    for (int ni = 0; ni < 4; ++ni) {
      const int col = n0 + wc * 64 + ni * 16 + lr;
      if (EPI == 0) {
        const int part = col / 768;
        const int e = col - part * 768;
        const int h = e / 96, d = e - (e / 96) * 96;
        const float* bb = part == 0 ? b0 : part == 1 ? b1 : b2;
        const float bv = bb[e];
#pragma unroll
        for (int j = 0; j < 4; ++j) {
          const int row = rbase + j;
          const int b = row >> 10, s = row & 1023;
          const int bh = b * 8 + h;
          const float v = acc[mi][ni][j] + bv;
          if (part == 0)      Qo[((size_t)bh * 1024 + s) * 96 + d] = (_Float16)v;
          else if (part == 1) Ko[((size_t)bh * 1024 + s) * 96 + d] = (_Float16)v;
          else                Vto[((size_t)bh * 96 + d) * 1024 + s] = (_Float16)v;
        }
      } else {
        const float bv = b0[col];
#pragma unroll
        for (int j = 0; j < 4; ++j) {
          const int row = rbase + j;
          Co[(size_t)row * 768 + col] = acc[mi][ni][j] + bv;
        }
      }
    }
  }
}

// ---------------- fused attention v5: single-pass + explicit SW pipelines ----------------
// Block = 4 waves = one 16-q-row tile; wave w owns k-slice [w*256, w*256+256).
// Fixes vs v4: __launch_bounds__(256,1) so the 64-reg score array never spills;
// depth-4 software-pipelined K and V fragment loads (compile-time slot indices).
__global__ __launch_bounds__(256, 1) void attn(const _Float16* __restrict__ Q,
                                               const _Float16* __restrict__ Kk,
                                               const _Float16* __restrict__ Vt,
                                               float* __restrict__ probs,
                                               _Float16* __restrict__ ctx) {
  // per-wave 8448B region: first Ps fp16 [16][264], later ctx-partial f32 [16][100]
  __shared__ __align__(16) char lds[4][8448];
  __shared__ float lsb[4][16];
  const int tid = threadIdx.x, w = tid >> 6, l = tid & 63;
  const int lr = l & 15, lk = l >> 4;
  const int id = blockIdx.x;
  const int lid = (id & 7) * 1024 + (id >> 3);   // XCD-chunked
  const int bh = lid >> 6, qt = lid & 63;
  const int q0 = qt * 16;
  const float SC = 0.10206207261596577f * 1.4426950408889634f;  // (1/sqrt(96)) * log2(e)

  _Float16* Ps = (_Float16*)lds[w];   // [16][264] (+8 pad)
  float* cbw = (float*)lds[w];        // [16][100] (reused after PV)

  const _Float16* kbh = Kk + (size_t)bh * 1024 * 96;
  const _Float16* vbh = Vt + (size_t)bh * 96 * 1024;

  // Q B-fragments (all waves load the same 16 q-rows)
  half8 bq[3];
  {
    const _Float16* qrow = Q + ((size_t)bh * 1024 + q0 + lr) * 96;
#pragma unroll
    for (int kk = 0; kk < 3; ++kk) bq[kk] = *(const half8*)(qrow + kk * 32 + lk * 8);
  }

  // ---- QK^T: depth-4 pipelined K-fragment loads, scores in registers ----
  f32x4 s[16];
  const _Float16* kb = kbh + (size_t)(w * 256 + lr) * 96 + lk * 8;
  half8 kf[4][3];
#pragma unroll
  for (int ct = 0; ct < 4; ++ct)
#pragma unroll
    for (int kk = 0; kk < 3; ++kk)
      kf[ct][kk] = *(const half8*)(kb + (size_t)ct * (16 * 96) + kk * 32);
#pragma unroll
  for (int ct = 0; ct < 16; ++ct) {
    const int slot = ct & 3;
    f32x4 acc = {0.f, 0.f, 0.f, 0.f};
#pragma unroll
    for (int kk = 0; kk < 3; ++kk)
      acc = __builtin_amdgcn_mfma_f32_16x16x32_f16(kf[slot][kk], bq[kk], acc, 0, 0, 0);
    if (ct + 4 < 16) {
#pragma unroll
      for (int kk = 0; kk < 3; ++kk)
        kf[slot][kk] = *(const half8*)(kb + (size_t)(ct + 4) * (16 * 96) + kk * 32);
    }
    s[ct] = acc;
  }

  // ---- exp (in place) + per-lane partial sum ----
  float psum = 0.f;
#pragma unroll
  for (int ct = 0; ct < 16; ++ct)
#pragma unroll
    for (int j = 0; j < 4; ++j) {
      const float e = __builtin_amdgcn_exp2f(s[ct][j] * SC);
      s[ct][j] = e;
      psum += e;
    }
  psum += __shfl_xor(psum, 16);
  psum += __shfl_xor(psum, 32);
  if (lk == 0) lsb[w][lr] = psum;
  __syncthreads();
  const float invl = 1.f / (lsb[0][lr] + lsb[1][lr] + lsb[2][lr] + lsb[3][lr]);

  // ---- normalized probs stores (fire-and-forget) + P redistribute ----
  float* pb = probs + ((size_t)bh << 20) + (size_t)(q0 + lr) * 1024 + w * 256 + lk * 4;
#pragma unroll
  for (int ct = 0; ct < 16; ++ct) {
    float4 p4;
    half4 ph;
#pragma unroll
    for (int j = 0; j < 4; ++j) {
      const float p = s[ct][j] * invl;
      ((float*)&p4)[j] = p;
      ph[j] = (_Float16)p;
    }
    *(float4*)(pb + ct * 16) = p4;
    *(half4*)&Ps[lr * 264 + ct * 16 + lk * 4] = ph;
  }

  // ---- PV: hoist all 8 P fragments from LDS, depth-4 pipelined V loads ----
  half8 pa[8];
#pragma unroll
  for (int kk = 0; kk < 8; ++kk)
    pa[kk] = *(const half8*)&Ps[lr * 264 + kk * 32 + lk * 8];

  f32x4 cacc[6] = {};
  const _Float16* vb0 = vbh + (size_t)lr * 1024 + w * 256 + lk * 8;
  half8 vf[4];
#pragma unroll
  for (int i = 0; i < 4; ++i)
    vf[i] = *(const half8*)(vb0 + (size_t)(i >> 3) * (16 * 1024) + (i & 7) * 32);
#pragma unroll
  for (int i = 0; i < 48; ++i) {         // i = dt*8 + kk
    const int slot = i & 3;
    cacc[i >> 3] = __builtin_amdgcn_mfma_f32_16x16x32_f16(pa[i & 7], vf[slot], cacc[i >> 3], 0, 0, 0);
    if (i + 4 < 48) {
      const int n = i + 4;
      vf[slot] = *(const half8*)(vb0 + (size_t)(n >> 3) * (16 * 1024) + (n & 7) * 32);
    }
  }

  // ---- wave-local partial -> LDS f32 (own region; per-wave DS ordering) ----
#pragma unroll
  for (int dt = 0; dt < 6; ++dt)
#pragma unroll
    for (int j = 0; j < 4; ++j)
      cbw[(lk * 4 + j) * 100 + dt * 16 + lr] = cacc[dt][j];
  __syncthreads();

  // ---- cross-wave reduce + ctx store: 1536 elems, 6 per thread ----
  const int q = tid >> 4;
  const int d0 = (tid & 15) * 6;
  const int b = bh >> 3, h = bh & 7;
  _Float16* cg = ctx + ((size_t)(b * 1024 + q0 + q)) * 768 + h * 96 + d0;
#pragma unroll
  for (int e = 0; e < 6; ++e) {
    float v = 0.f;
#pragma unroll
    for (int ww = 0; ww < 4; ++ww) v += ((const float*)lds[ww])[q * 100 + d0 + e];
    cg[e] = (_Float16)v;
  }
}

extern "C" void kernel_launch(void* const* d_in, const int* in_sizes, int n_in,
                              void* d_out, int out_size, void* d_ws, size_t ws_size,
                              hipStream_t stream) {
  (void)in_sizes; (void)n_in; (void)out_size; (void)ws_size;
  const float* X  = (const float*)d_in[0];
  const float* Wq = (const float*)d_in[1];
  const float* bq = (const float*)d_in[2];
  const float* Wk = (const float*)d_in[3];
  const float* bk = (const float*)d_in[4];
  const float* Wv = (const float*)d_in[5];
  const float* bv = (const float*)d_in[6];
  const float* Wo = (const float*)d_in[7];
  const float* bo = (const float*)d_in[8];

  char* ws = (char*)d_ws;
  _Float16* Xh    = (_Float16*)(ws + 0);          // 16384x768 fp16      (25165824 B)
  _Float16* Wqkvt = (_Float16*)(ws + 25165824);   // 2304x768 fp16       ( 3538944 B)
  _Float16* Wot   = (_Float16*)(ws + 28704768);   // 768x768 fp16        ( 1179648 B)
  _Float16* Qh    = (_Float16*)(ws + 29884416);   // [128][1024][96]     (25165824 B)
  _Float16* Kh    = (_Float16*)(ws + 55050240);   // [128][1024][96]     (25165824 B)
  _Float16* Vth   = (_Float16*)(ws + 80216064);   // [128][96][1024]     (25165824 B)
  _Float16* Ctx   = (_Float16*)(ws + 105381888);  // [16384][768]        (25165824 B)

  float* out   = (float*)d_out;
  float* probs = out + 12582912;                  // [16][8][1024][1024]

  cvt_x<<<dim3(6144), dim3(256), 0, stream>>>(X, Xh);
  cvt_w<<<dim3(9216), dim3(256), 0, stream>>>(Wq, Wk, Wv, Wo, Wqkvt, Wot);
  gemm_f16<0><<<dim3(18, 128), dim3(256), 0, stream>>>(Xh, Wqkvt, bq, bk, bv, Qh, Kh, Vth, nullptr);
  attn<<<dim3(8192), dim3(256), 0, stream>>>(Qh, Kh, Vth, probs, Ctx);
  gemm_f16<1><<<dim3(6, 128), dim3(256), 0, stream>>>(Ctx, Wot, bo, bo, bo, nullptr, nullptr, nullptr, out);
}

// Round 6
// 496.342 us; speedup vs baseline: 1.4443x; 1.2406x over previous
//
#include <hip/hip_runtime.h>

typedef _Float16 half8 __attribute__((ext_vector_type(8)));
typedef _Float16 half4 __attribute__((ext_vector_type(4)));
typedef float f32x4 __attribute__((ext_vector_type(4)));

__device__ __forceinline__ void lds_load16(const void* g, void* l) {
  __builtin_amdgcn_global_load_lds((const __attribute__((address_space(1))) void*)g,
                                   (__attribute__((address_space(3))) void*)l, 16, 0, 0);
}

// ---------------- convert X f32 -> fp16 ----------------
__global__ __launch_bounds__(256) void cvt_x(const float* __restrict__ in,
                                             _Float16* __restrict__ out) {
  int i = blockIdx.x * 256 + threadIdx.x;      // one thread = 8 elements
  const float4* p = (const float4*)(in + (size_t)i * 8);
  float4 a = p[0], b = p[1];
  half8 v;
  v[0] = (_Float16)a.x; v[1] = (_Float16)a.y; v[2] = (_Float16)a.z; v[3] = (_Float16)a.w;
  v[4] = (_Float16)b.x; v[5] = (_Float16)b.y; v[6] = (_Float16)b.z; v[7] = (_Float16)b.w;
  *(half8*)(out + (size_t)i * 8) = v;
}

// ------- convert + transpose weights: Wt[n][k] = W[k][n], fp16 -------
__global__ __launch_bounds__(256) void cvt_w(const float* __restrict__ Wq, const float* __restrict__ Wk,
                                             const float* __restrict__ Wv, const float* __restrict__ Wo,
                                             _Float16* __restrict__ Wqkvt, _Float16* __restrict__ Wot) {
  int id = blockIdx.x * 256 + threadIdx.x;     // 0 .. 4*589824-1
  int part = id / 589824;
  int r = id - part * 589824;
  int k = r / 768;
  int n = r - k * 768;
  const float* W = part == 0 ? Wq : part == 1 ? Wk : part == 2 ? Wv : Wo;
  _Float16 v = (_Float16)W[(size_t)k * 768 + n];   // coalesced read over n
  if (part < 3) Wqkvt[((size_t)(part * 768 + n)) * 768 + k] = v;
  else          Wot[(size_t)n * 768 + k] = v;
}

// ---------------- fp16 MFMA GEMM, 128x128 tile, BK=32 ----------------
// EPI=0 epilogue scatters Q,K,V into FRAGMENT-MAJOR swizzled layouts so the
// attention kernel's MFMA operand loads are single coalesced 1KB wave-reads:
//   swzQ/swzK: [bh][t=s>>4][kk=d>>5][lane=(d&31)>>3*16 + (s&15)] half8(e=d&7)
//   swzV:      [bh][dt=d>>4][kc=s>>5][lane=(s&31)>>3*16 + (d&15)] half8(e=s&7)
template <int EPI>
__global__ __launch_bounds__(256) void gemm_f16(
    const _Float16* __restrict__ A, const _Float16* __restrict__ Bt,
    const float* __restrict__ b0, const float* __restrict__ b1, const float* __restrict__ b2,
    _Float16* __restrict__ Qo, _Float16* __restrict__ Ko, _Float16* __restrict__ Vto,
    float* __restrict__ Co) {
  const int K = 768;
  __shared__ _Float16 As[128 * 32];
  __shared__ _Float16 Bs[128 * 32];
  const int tid = threadIdx.x, w = tid >> 6, l = tid & 63;
  const int lr = l & 15, lk = l >> 4;
  const int m0 = blockIdx.y * 128, n0 = blockIdx.x * 128;
  const int wr = w >> 1, wc = w & 1;
  f32x4 acc[4][4] = {};
  const int arow = tid >> 2;
  const int acolb = (tid & 3) * 16;

  for (int k0 = 0; k0 < K; k0 += 32) {
    __syncthreads();
#pragma unroll
    for (int c = 0; c < 2; ++c) {
      lds_load16((const char*)(A + (size_t)(m0 + c * 64 + arow) * K + k0) + acolb,
                 (char*)As + c * 4096 + w * 1024);
      lds_load16((const char*)(Bt + (size_t)(n0 + c * 64 + arow) * K + k0) + acolb,
                 (char*)Bs + c * 4096 + w * 1024);
    }
    __syncthreads();
    half8 af[4], bf[4];
#pragma unroll
    for (int mi = 0; mi < 4; ++mi) af[mi] = *(const half8*)&As[(wr * 64 + mi * 16 + lr) * 32 + lk * 8];
#pragma unroll
    for (int ni = 0; ni < 4; ++ni) bf[ni] = *(const half8*)&Bs[(wc * 64 + ni * 16 + lr) * 32 + lk * 8];
#pragma unroll
    for (int mi = 0; mi < 4; ++mi)
#pragma unroll
      for (int ni = 0; ni < 4; ++ni)
        acc[mi][ni] = __builtin_amdgcn_mfma_f32_16x16x32_f16(af[mi], bf[ni], acc[mi][ni], 0, 0, 0);
  }

#pragma unroll
  for (int mi = 0; mi < 4; ++mi) {
    const int rbase = m0 + wr * 64 + mi * 16 + lk * 4;
#pragma unroll
    for (int ni = 0; ni < 4; ++ni) {
      const int col = n0 + wc * 64 + ni * 16 + lr;
      if (EPI == 0) {
        const int part = col / 768;
        const int e = col - part * 768;
        const int h = e / 96, d = e - (e / 96) * 96;
        const float* bb = part == 0 ? b0 : part == 1 ? b1 : b2;
        const float bv = bb[e];
#pragma unroll
        for (int j = 0; j < 4; ++j) {
          const int row = rbase + j;
          const int b = row >> 10, s = row & 1023;
          const int bh = b * 8 + h;
          const _Float16 v = (_Float16)(acc[mi][ni][j] + bv);
          if (part < 2) {
            // fragment-major Q/K: tile t=s>>4, kk=d>>5, lane=((d&31)>>3)*16+(s&15), elem=d&7
            const size_t idx = ((((size_t)(bh * 64 + (s >> 4)) * 3 + (d >> 5)) * 64
                                + ((d & 31) >> 3) * 16 + (s & 15)) << 3) + (d & 7);
            if (part == 0) Qo[idx] = v; else Ko[idx] = v;
          } else {
            // fragment-major V: dt=d>>4, kc=s>>5, lane=((s&31)>>3)*16+(d&15), elem=s&7
            const size_t idx = ((((size_t)(bh * 6 + (d >> 4)) * 32 + (s >> 5)) * 64
                                + ((s & 31) >> 3) * 16 + (d & 15)) << 3) + (s & 7);
            Vto[idx] = v;
          }
        }
      } else {
        const float bv = b0[col];
#pragma unroll
        for (int j = 0; j < 4; ++j) {
          const int row = rbase + j;
          Co[(size_t)row * 768 + col] = acc[mi][ni][j] + bv;
        }
      }
    }
  }
}

// ---------------- fused attention v6: 8 waves, coalesced fragment loads ----------------
// Block = 8 waves (512 thr) = one 16-q-row tile; wave w owns k-slice [w*128, w*128+128).
// All Q/K/V fragment loads are coalesced 1KB wave-reads from fragment-major layouts.
// s[8] = 32 score VGPRs (statically indexed) -> no spill. 2 barriers total.
__global__ __launch_bounds__(512, 4) void attn(const _Float16* __restrict__ swzQ,
                                               const _Float16* __restrict__ swzK,
                                               const _Float16* __restrict__ swzV,
                                               float* __restrict__ probs,
                                               _Float16* __restrict__ ctx) {
  // per-wave 6656B region: Ps fp16 [16][136] (4352B), then ctx-partial f32 [16][100] (6400B)
  __shared__ __align__(16) char lds[8][6656];
  __shared__ float lsb[8][16];
  const int tid = threadIdx.x, w = tid >> 6, l = tid & 63;
  const int lr = l & 15, lk = l >> 4;
  const int id = blockIdx.x;
  const int lid = (id & 7) * 1024 + (id >> 3);   // XCD-chunked
  const int bh = lid >> 6, qt = lid & 63;
  const int q0 = qt * 16;
  const float SC = 0.10206207261596577f * 1.4426950408889634f;  // (1/sqrt(96)) * log2(e)

  _Float16* Ps = (_Float16*)lds[w];   // [16][136]
  float* cbw = (float*)lds[w];        // [16][100] (reused after PV)

  // ---- Q fragments: coalesced ----
  const half8* qb = (const half8*)swzQ + (size_t)(bh * 64 + qt) * 192;  // 3*64 half8
  half8 bq[3];
#pragma unroll
  for (int kk = 0; kk < 3; ++kk) bq[kk] = qb[kk * 64 + l];

  // ---- QK^T for this wave's 128-k slice: 24 coalesced loads, scores in 8 f32x4 ----
  const half8* kb = (const half8*)swzK + (size_t)(bh * 64 + w * 8) * 192;
  f32x4 s[8];
#pragma unroll
  for (int ct = 0; ct < 8; ++ct) {
    f32x4 acc = {0.f, 0.f, 0.f, 0.f};
#pragma unroll
    for (int kk = 0; kk < 3; ++kk) {
      half8 kf = kb[(ct * 3 + kk) * 64 + l];
      acc = __builtin_amdgcn_mfma_f32_16x16x32_f16(kf, bq[kk], acc, 0, 0, 0);
    }
    s[ct] = acc;
  }

  // ---- exp + per-lane partial sum; cross-wave reduce ----
  float psum = 0.f;
#pragma unroll
  for (int ct = 0; ct < 8; ++ct)
#pragma unroll
    for (int j = 0; j < 4; ++j) {
      const float e = __builtin_amdgcn_exp2f(s[ct][j] * SC);
      s[ct][j] = e;
      psum += e;
    }
  psum += __shfl_xor(psum, 16);
  psum += __shfl_xor(psum, 32);
  if (lk == 0) lsb[w][lr] = psum;
  __syncthreads();
  float lt = 0.f;
#pragma unroll
  for (int ww = 0; ww < 8; ++ww) lt += lsb[ww][lr];
  const float invl = 1.f / lt;

  // ---- normalized probs stores + fp16 P to wave-local LDS ----
  float* pb = probs + ((size_t)bh << 20) + (size_t)(q0 + lr) * 1024 + w * 128 + lk * 4;
#pragma unroll
  for (int ct = 0; ct < 8; ++ct) {
    float4 p4;
    half4 ph;
#pragma unroll
    for (int j = 0; j < 4; ++j) {
      const float p = s[ct][j] * invl;
      ((float*)&p4)[j] = p;
      ph[j] = (_Float16)p;
    }
    *(float4*)(pb + ct * 16) = p4;
    *(half4*)&Ps[lr * 136 + ct * 16 + lk * 4] = ph;
  }

  // ---- PV over this wave's slice: V loads coalesced; partial ctx[16 x 96] ----
  f32x4 cacc[6] = {};
  const half8* vb0 = (const half8*)swzV + (size_t)bh * 12288;  // 6*32*64 half8
#pragma unroll
  for (int kk = 0; kk < 4; ++kk) {
    half8 pa = *(const half8*)&Ps[lr * 136 + kk * 32 + lk * 8];
#pragma unroll
    for (int dt = 0; dt < 6; ++dt) {
      half8 vb = vb0[(dt * 32 + w * 4 + kk) * 64 + l];
      cacc[dt] = __builtin_amdgcn_mfma_f32_16x16x32_f16(pa, vb, cacc[dt], 0, 0, 0);
    }
  }

  // ---- wave-local partial -> own LDS region (per-wave DS ordering) ----
#pragma unroll
  for (int dt = 0; dt < 6; ++dt)
#pragma unroll
    for (int j = 0; j < 4; ++j)
      cbw[(lk * 4 + j) * 100 + dt * 16 + lr] = cacc[dt][j];
  __syncthreads();

  // ---- cross-wave reduce (8 partials) + ctx store: 1536 elems, 3 per thread ----
  const int q = tid >> 5;            // 0..15
  const int d0 = (tid & 31) * 3;     // 0..93
  const int b = bh >> 3, h = bh & 7;
  _Float16* cg = ctx + ((size_t)(b * 1024 + q0 + q)) * 768 + h * 96 + d0;
#pragma unroll
  for (int e = 0; e < 3; ++e) {
    float v = 0.f;
#pragma unroll
    for (int ww = 0; ww < 8; ++ww) v += ((const float*)lds[ww])[q * 100 + d0 + e];
    cg[e] = (_Float16)v;
  }
}

extern "C" void kernel_launch(void* const* d_in, const int* in_sizes, int n_in,
                              void* d_out, int out_size, void* d_ws, size_t ws_size,
                              hipStream_t stream) {
  (void)in_sizes; (void)n_in; (void)out_size; (void)ws_size;
  const float* X  = (const float*)d_in[0];
  const float* Wq = (const float*)d_in[1];
  const float* bq = (const float*)d_in[2];
  const float* Wk = (const float*)d_in[3];
  const float* bk = (const float*)d_in[4];
  const float* Wv = (const float*)d_in[5];
  const float* bv = (const float*)d_in[6];
  const float* Wo = (const float*)d_in[7];
  const float* bo = (const float*)d_in[8];

  char* ws = (char*)d_ws;
  _Float16* Xh    = (_Float16*)(ws + 0);          // 16384x768 fp16      (25165824 B)
  _Float16* Wqkvt = (_Float16*)(ws + 25165824);   // 2304x768 fp16       ( 3538944 B)
  _Float16* Wot   = (_Float16*)(ws + 28704768);   // 768x768 fp16        ( 1179648 B)
  _Float16* Qh    = (_Float16*)(ws + 29884416);   // swzQ                (25165824 B)
  _Float16* Kh    = (_Float16*)(ws + 55050240);   // swzK                (25165824 B)
  _Float16* Vth   = (_Float16*)(ws + 80216064);   // swzV                (25165824 B)
  _Float16* Ctx   = (_Float16*)(ws + 105381888);  // [16384][768]        (25165824 B)

  float* out   = (float*)d_out;
  float* probs = out + 12582912;                  // [16][8][1024][1024]

  cvt_x<<<dim3(6144), dim3(256), 0, stream>>>(X, Xh);
  cvt_w<<<dim3(9216), dim3(256), 0, stream>>>(Wq, Wk, Wv, Wo, Wqkvt, Wot);
  gemm_f16<0><<<dim3(18, 128), dim3(256), 0, stream>>>(Xh, Wqkvt, bq, bk, bv, Qh, Kh, Vth, nullptr);
  attn<<<dim3(8192), dim3(512), 0, stream>>>(Qh, Kh, Vth, probs, Ctx);
  gemm_f16<1><<<dim3(6, 128), dim3(256), 0, stream>>>(Ctx, Wot, bo, bo, bo, nullptr, nullptr, nullptr, out);
}

// Round 7
// 376.194 us; speedup vs baseline: 1.9056x; 1.3194x over previous
//
#include <hip/hip_runtime.h>

typedef _Float16 half8 __attribute__((ext_vector_type(8)));
typedef _Float16 half4 __attribute__((ext_vector_type(4)));
typedef float f32x4 __attribute__((ext_vector_type(4)));

__device__ __forceinline__ void lds_load16(const void* g, void* l) {
  __builtin_amdgcn_global_load_lds((const __attribute__((address_space(1))) void*)g,
                                   (__attribute__((address_space(3))) void*)l, 16, 0, 0);
}

// ---------------- convert X f32 -> fp16 ----------------
__global__ __launch_bounds__(256) void cvt_x(const float* __restrict__ in,
                                             _Float16* __restrict__ out) {
  int i = blockIdx.x * 256 + threadIdx.x;      // one thread = 8 elements
  const float4* p = (const float4*)(in + (size_t)i * 8);
  float4 a = p[0], b = p[1];
  half8 v;
  v[0] = (_Float16)a.x; v[1] = (_Float16)a.y; v[2] = (_Float16)a.z; v[3] = (_Float16)a.w;
  v[4] = (_Float16)b.x; v[5] = (_Float16)b.y; v[6] = (_Float16)b.z; v[7] = (_Float16)b.w;
  *(half8*)(out + (size_t)i * 8) = v;
}

// ------- convert + transpose weights: Wt[n][k] = W[k][n], fp16 -------
__global__ __launch_bounds__(256) void cvt_w(const float* __restrict__ Wq, const float* __restrict__ Wk,
                                             const float* __restrict__ Wv, const float* __restrict__ Wo,
                                             _Float16* __restrict__ Wqkvt, _Float16* __restrict__ Wot) {
  int id = blockIdx.x * 256 + threadIdx.x;     // 0 .. 4*589824-1
  int part = id / 589824;
  int r = id - part * 589824;
  int k = r / 768;
  int n = r - k * 768;
  const float* W = part == 0 ? Wq : part == 1 ? Wk : part == 2 ? Wv : Wo;
  _Float16 v = (_Float16)W[(size_t)k * 768 + n];   // coalesced read over n
  if (part < 3) Wqkvt[((size_t)(part * 768 + n)) * 768 + k] = v;
  else          Wot[(size_t)n * 768 + k] = v;
}

// ---------------- fp16 MFMA GEMM, 128x128 tile, BK=32 ----------------
// EPI=0 epilogue scatters Q,K,V into FRAGMENT-MAJOR swizzled layouts so the
// attention kernel's MFMA operand loads are single coalesced 1KB wave-reads.
template <int EPI>
__global__ __launch_bounds__(256) void gemm_f16(
    const _Float16* __restrict__ A, const _Float16* __restrict__ Bt,
    const float* __restrict__ b0, const float* __restrict__ b1, const float* __restrict__ b2,
    _Float16* __restrict__ Qo, _Float16* __restrict__ Ko, _Float16* __restrict__ Vto,
    float* __restrict__ Co) {
  const int K = 768;
  __shared__ _Float16 As[128 * 32];
  __shared__ _Float16 Bs[128 * 32];
  const int tid = threadIdx.x, w = tid >> 6, l = tid & 63;
  const int lr = l & 15, lk = l >> 4;
  const int m0 = blockIdx.y * 128, n0 = blockIdx.x * 128;
  const int wr = w >> 1, wc = w & 1;
  f32x4 acc[4][4] = {};
  const int arow = tid >> 2;
  const int acolb = (tid & 3) * 16;

  for (int k0 = 0; k0 < K; k0 += 32) {
    __syncthreads();
#pragma unroll
    for (int c = 0; c < 2; ++c) {
      lds_load16((const char*)(A + (size_t)(m0 + c * 64 + arow) * K + k0) + acolb,
                 (char*)As + c * 4096 + w * 1024);
      lds_load16((const char*)(Bt + (size_t)(n0 + c * 64 + arow) * K + k0) + acolb,
                 (char*)Bs + c * 4096 + w * 1024);
    }
    __syncthreads();
    half8 af[4], bf[4];
#pragma unroll
    for (int mi = 0; mi < 4; ++mi) af[mi] = *(const half8*)&As[(wr * 64 + mi * 16 + lr) * 32 + lk * 8];
#pragma unroll
    for (int ni = 0; ni < 4; ++ni) bf[ni] = *(const half8*)&Bs[(wc * 64 + ni * 16 + lr) * 32 + lk * 8];
#pragma unroll
    for (int mi = 0; mi < 4; ++mi)
#pragma unroll
      for (int ni = 0; ni < 4; ++ni)
        acc[mi][ni] = __builtin_amdgcn_mfma_f32_16x16x32_f16(af[mi], bf[ni], acc[mi][ni], 0, 0, 0);
  }

#pragma unroll
  for (int mi = 0; mi < 4; ++mi) {
    const int rbase = m0 + wr * 64 + mi * 16 + lk * 4;
#pragma unroll
    for (int ni = 0; ni < 4; ++ni) {
      const int col = n0 + wc * 64 + ni * 16 + lr;
      if (EPI == 0) {
        const int part = col / 768;
        const int e = col - part * 768;
        const int h = e / 96, d = e - (e / 96) * 96;
        const float* bb = part == 0 ? b0 : part == 1 ? b1 : b2;
        const float bv = bb[e];
#pragma unroll
        for (int j = 0; j < 4; ++j) {
          const int row = rbase + j;
          const int b = row >> 10, s = row & 1023;
          const int bh = b * 8 + h;
          const _Float16 v = (_Float16)(acc[mi][ni][j] + bv);
          if (part < 2) {
            const size_t idx = ((((size_t)(bh * 64 + (s >> 4)) * 3 + (d >> 5)) * 64
                                + ((d & 31) >> 3) * 16 + (s & 15)) << 3) + (d & 7);
            if (part == 0) Qo[idx] = v; else Ko[idx] = v;
          } else {
            const size_t idx = ((((size_t)(bh * 6 + (d >> 4)) * 32 + (s >> 5)) * 64
                                + ((s & 31) >> 3) * 16 + (d & 15)) << 3) + (s & 7);
            Vto[idx] = v;
          }
        }
      } else {
        const float bv = b0[col];
#pragma unroll
        for (int j = 0; j < 4; ++j) {
          const int row = rbase + j;
          Co[(size_t)row * 768 + col] = acc[mi][ni][j] + bv;
        }
      }
    }
  }
}

// ---------------- fused attention v7 ----------------
// 8 waves/block, wave w owns k-slice [w*128, w*128+128) of one 16-q-row tile.
// ALL 51 Q/K/V fragment loads hoisted upfront into registers (~270 VGPR,
// legal: LDS caps us at 2 blocks/CU = 4 waves/SIMD -> 512 VGPR budget).
// Probs: normalized f32 P tile staged in wave-local LDS, re-read 2-rows-per-
// wave-store -> 512B segments, written NONTEMPORAL (bypass L2).
__global__ __launch_bounds__(512, 4) void attn(const _Float16* __restrict__ swzQ,
                                               const _Float16* __restrict__ swzK,
                                               const _Float16* __restrict__ swzV,
                                               float* __restrict__ probs,
                                               _Float16* __restrict__ ctx) {
  __shared__ __align__(16) float Pf[8][16][132];  // per-wave f32 P tile (8448B)
  __shared__ float lsb[8][16];
  const int tid = threadIdx.x, w = tid >> 6, l = tid & 63;
  const int lr = l & 15, lk = l >> 4;
  const int id = blockIdx.x;
  const int lid = (id & 7) * 1024 + (id >> 3);   // XCD-chunked
  const int bh = lid >> 6, qt = lid & 63;
  const int q0 = qt * 16;
  const float SC = 0.10206207261596577f * 1.4426950408889634f;  // (1/sqrt(96)) * log2(e)

  // ---- issue ALL fragment loads upfront (coalesced 1KB wave-reads) ----
  const half8* qb  = (const half8*)swzQ + (size_t)(bh * 64 + qt) * 192;
  const half8* kb  = (const half8*)swzK + (size_t)(bh * 64 + w * 8) * 192;
  const half8* vb0 = (const half8*)swzV + (size_t)bh * 12288;
  half8 bq[3];
#pragma unroll
  for (int kk = 0; kk < 3; ++kk) bq[kk] = qb[kk * 64 + l];
  half8 kf[8][3];
#pragma unroll
  for (int ct = 0; ct < 8; ++ct)
#pragma unroll
    for (int kk = 0; kk < 3; ++kk) kf[ct][kk] = kb[(ct * 3 + kk) * 64 + l];
  half8 vf[6][4];
#pragma unroll
  for (int dt = 0; dt < 6; ++dt)
#pragma unroll
    for (int kk = 0; kk < 4; ++kk) vf[dt][kk] = vb0[(dt * 32 + w * 4 + kk) * 64 + l];

  // ---- QK^T: scores in 8 f32x4 ----
  f32x4 s[8];
#pragma unroll
  for (int ct = 0; ct < 8; ++ct) {
    f32x4 acc = {0.f, 0.f, 0.f, 0.f};
#pragma unroll
    for (int kk = 0; kk < 3; ++kk)
      acc = __builtin_amdgcn_mfma_f32_16x16x32_f16(kf[ct][kk], bq[kk], acc, 0, 0, 0);
    s[ct] = acc;
  }

  // ---- exp + per-lane partial sum; cross-wave reduce ----
  float psum = 0.f;
#pragma unroll
  for (int ct = 0; ct < 8; ++ct)
#pragma unroll
    for (int j = 0; j < 4; ++j) {
      const float e = __builtin_amdgcn_exp2f(s[ct][j] * SC);
      s[ct][j] = e;
      psum += e;
    }
  psum += __shfl_xor(psum, 16);
  psum += __shfl_xor(psum, 32);
  if (lk == 0) lsb[w][lr] = psum;
  __syncthreads();
  float lt = 0.f;
#pragma unroll
  for (int ww = 0; ww < 8; ++ww) lt += lsb[ww][lr];
  const float invl = 1.f / lt;

  // ---- normalized f32 P -> wave-local LDS tile ----
#pragma unroll
  for (int ct = 0; ct < 8; ++ct) {
    f32x4 p4;
#pragma unroll
    for (int j = 0; j < 4; ++j) p4[j] = s[ct][j] * invl;
    *(f32x4*)&Pf[w][lr][ct * 16 + lk * 4] = p4;
  }

  // ---- probs: repacked reads (2 rows x 512B) -> NONTEMPORAL stores ----
  {
    float* pbase = probs + ((size_t)bh << 20) + (size_t)q0 * 1024 + w * 128;
    const int qh = l >> 5, c4 = (l & 31) * 4;
#pragma unroll
    for (int r2 = 0; r2 < 8; ++r2) {
      const int q = r2 * 2 + qh;
      f32x4 v = *(const f32x4*)&Pf[w][q][c4];
      __builtin_nontemporal_store(v, (f32x4*)(pbase + (size_t)q * 1024 + c4));
    }
  }

  // ---- PV: A-frags converted from f32 LDS tile; V already in registers ----
  f32x4 cacc[6] = {};
#pragma unroll
  for (int kk = 0; kk < 4; ++kk) {
    f32x4 a0 = *(const f32x4*)&Pf[w][lr][kk * 32 + lk * 8];
    f32x4 a1 = *(const f32x4*)&Pf[w][lr][kk * 32 + lk * 8 + 4];
    half8 pa;
#pragma unroll
    for (int e = 0; e < 4; ++e) { pa[e] = (_Float16)a0[e]; pa[4 + e] = (_Float16)a1[e]; }
#pragma unroll
    for (int dt = 0; dt < 6; ++dt)
      cacc[dt] = __builtin_amdgcn_mfma_f32_16x16x32_f16(pa, vf[dt][kk], cacc[dt], 0, 0, 0);
  }

  // ---- wave-local partial -> own LDS region (per-wave DS ordering) ----
  float* cbw = (float*)&Pf[w][0][0];   // [16][100] reuse
#pragma unroll
  for (int dt = 0; dt < 6; ++dt)
#pragma unroll
    for (int j = 0; j < 4; ++j)
      cbw[(lk * 4 + j) * 100 + dt * 16 + lr] = cacc[dt][j];
  __syncthreads();

  // ---- cross-wave reduce (8 partials) + ctx store ----
  const int q = tid >> 5;            // 0..15
  const int d0 = (tid & 31) * 3;     // 0..93
  const int b = bh >> 3, h = bh & 7;
  _Float16* cg = ctx + ((size_t)(b * 1024 + q0 + q)) * 768 + h * 96 + d0;
#pragma unroll
  for (int e = 0; e < 3; ++e) {
    float v = 0.f;
#pragma unroll
    for (int ww = 0; ww < 8; ++ww) v += ((const float*)&Pf[ww][0][0])[q * 100 + d0 + e];
    cg[e] = (_Float16)v;
  }
}

extern "C" void kernel_launch(void* const* d_in, const int* in_sizes, int n_in,
                              void* d_out, int out_size, void* d_ws, size_t ws_size,
                              hipStream_t stream) {
  (void)in_sizes; (void)n_in; (void)out_size; (void)ws_size;
  const float* X  = (const float*)d_in[0];
  const float* Wq = (const float*)d_in[1];
  const float* bq = (const float*)d_in[2];
  const float* Wk = (const float*)d_in[3];
  const float* bk = (const float*)d_in[4];
  const float* Wv = (const float*)d_in[5];
  const float* bv = (const float*)d_in[6];
  const float* Wo = (const float*)d_in[7];
  const float* bo = (const float*)d_in[8];

  char* ws = (char*)d_ws;
  _Float16* Xh    = (_Float16*)(ws + 0);          // 16384x768 fp16      (25165824 B)
  _Float16* Wqkvt = (_Float16*)(ws + 25165824);   // 2304x768 fp16       ( 3538944 B)
  _Float16* Wot   = (_Float16*)(ws + 28704768);   // 768x768 fp16        ( 1179648 B)
  _Float16* Qh    = (_Float16*)(ws + 29884416);   // swzQ                (25165824 B)
  _Float16* Kh    = (_Float16*)(ws + 55050240);   // swzK                (25165824 B)
  _Float16* Vth   = (_Float16*)(ws + 80216064);   // swzV                (25165824 B)
  _Float16* Ctx   = (_Float16*)(ws + 105381888);  // [16384][768]        (25165824 B)

  float* out   = (float*)d_out;
  float* probs = out + 12582912;                  // [16][8][1024][1024]

  cvt_x<<<dim3(6144), dim3(256), 0, stream>>>(X, Xh);
  cvt_w<<<dim3(9216), dim3(256), 0, stream>>>(Wq, Wk, Wv, Wo, Wqkvt, Wot);
  gemm_f16<0><<<dim3(18, 128), dim3(256), 0, stream>>>(Xh, Wqkvt, bq, bk, bv, Qh, Kh, Vth, nullptr);
  attn<<<dim3(8192), dim3(512), 0, stream>>>(Qh, Kh, Vth, probs, Ctx);
  gemm_f16<1><<<dim3(6, 128), dim3(256), 0, stream>>>(Ctx, Wot, bo, bo, bo, nullptr, nullptr, nullptr, out);
}

// Round 8
// 328.089 us; speedup vs baseline: 2.1850x; 1.1466x over previous
//
#include <hip/hip_runtime.h>

typedef _Float16 half8 __attribute__((ext_vector_type(8)));
typedef _Float16 half4 __attribute__((ext_vector_type(4)));
typedef float f32x4 __attribute__((ext_vector_type(4)));

__device__ __forceinline__ void lds_load16(const void* g, void* l) {
  __builtin_amdgcn_global_load_lds((const __attribute__((address_space(1))) void*)g,
                                   (__attribute__((address_space(3))) void*)l, 16, 0, 0);
}

// ---------------- convert X f32 -> fp16 ----------------
__global__ __launch_bounds__(256) void cvt_x(const float* __restrict__ in,
                                             _Float16* __restrict__ out) {
  int i = blockIdx.x * 256 + threadIdx.x;      // one thread = 8 elements
  const float4* p = (const float4*)(in + (size_t)i * 8);
  float4 a = p[0], b = p[1];
  half8 v;
  v[0] = (_Float16)a.x; v[1] = (_Float16)a.y; v[2] = (_Float16)a.z; v[3] = (_Float16)a.w;
  v[4] = (_Float16)b.x; v[5] = (_Float16)b.y; v[6] = (_Float16)b.z; v[7] = (_Float16)b.w;
  *(half8*)(out + (size_t)i * 8) = v;
}

// ------- convert + transpose weights: Wt[n][k] = W[k][n], fp16 -------
__global__ __launch_bounds__(256) void cvt_w(const float* __restrict__ Wq, const float* __restrict__ Wk,
                                             const float* __restrict__ Wv, const float* __restrict__ Wo,
                                             _Float16* __restrict__ Wqkvt, _Float16* __restrict__ Wot) {
  int id = blockIdx.x * 256 + threadIdx.x;     // 0 .. 4*589824-1
  int part = id / 589824;
  int r = id - part * 589824;
  int k = r / 768;
  int n = r - k * 768;
  const float* W = part == 0 ? Wq : part == 1 ? Wk : part == 2 ? Wv : Wo;
  _Float16 v = (_Float16)W[(size_t)k * 768 + n];   // coalesced read over n
  if (part < 3) Wqkvt[((size_t)(part * 768 + n)) * 768 + k] = v;
  else          Wot[(size_t)n * 768 + k] = v;
}

// ---------------- fp16 MFMA GEMM, 128x128 tile, BK=32 ----------------
// EPI=0 epilogue scatters Q,K,V into FRAGMENT-MAJOR swizzled layouts so the
// attention kernel's MFMA operand loads are single coalesced 1KB wave-reads.
template <int EPI>
__global__ __launch_bounds__(256) void gemm_f16(
    const _Float16* __restrict__ A, const _Float16* __restrict__ Bt,
    const float* __restrict__ b0, const float* __restrict__ b1, const float* __restrict__ b2,
    _Float16* __restrict__ Qo, _Float16* __restrict__ Ko, _Float16* __restrict__ Vto,
    float* __restrict__ Co) {
  const int K = 768;
  __shared__ _Float16 As[128 * 32];
  __shared__ _Float16 Bs[128 * 32];
  const int tid = threadIdx.x, w = tid >> 6, l = tid & 63;
  const int lr = l & 15, lk = l >> 4;
  const int m0 = blockIdx.y * 128, n0 = blockIdx.x * 128;
  const int wr = w >> 1, wc = w & 1;
  f32x4 acc[4][4] = {};
  const int arow = tid >> 2;
  const int acolb = (tid & 3) * 16;

  for (int k0 = 0; k0 < K; k0 += 32) {
    __syncthreads();
#pragma unroll
    for (int c = 0; c < 2; ++c) {
      lds_load16((const char*)(A + (size_t)(m0 + c * 64 + arow) * K + k0) + acolb,
                 (char*)As + c * 4096 + w * 1024);
      lds_load16((const char*)(Bt + (size_t)(n0 + c * 64 + arow) * K + k0) + acolb,
                 (char*)Bs + c * 4096 + w * 1024);
    }
    __syncthreads();
    half8 af[4], bf[4];
#pragma unroll
    for (int mi = 0; mi < 4; ++mi) af[mi] = *(const half8*)&As[(wr * 64 + mi * 16 + lr) * 32 + lk * 8];
#pragma unroll
    for (int ni = 0; ni < 4; ++ni) bf[ni] = *(const half8*)&Bs[(wc * 64 + ni * 16 + lr) * 32 + lk * 8];
#pragma unroll
    for (int mi = 0; mi < 4; ++mi)
#pragma unroll
      for (int ni = 0; ni < 4; ++ni)
        acc[mi][ni] = __builtin_amdgcn_mfma_f32_16x16x32_f16(af[mi], bf[ni], acc[mi][ni], 0, 0, 0);
  }

#pragma unroll
  for (int mi = 0; mi < 4; ++mi) {
    const int rbase = m0 + wr * 64 + mi * 16 + lk * 4;
#pragma unroll
    for (int ni = 0; ni < 4; ++ni) {
      const int col = n0 + wc * 64 + ni * 16 + lr;
      if (EPI == 0) {
        const int part = col / 768;
        const int e = col - part * 768;
        const int h = e / 96, d = e - (e / 96) * 96;
        const float* bb = part == 0 ? b0 : part == 1 ? b1 : b2;
        const float bv = bb[e];
#pragma unroll
        for (int j = 0; j < 4; ++j) {
          const int row = rbase + j;
          const int b = row >> 10, s = row & 1023;
          const int bh = b * 8 + h;
          const _Float16 v = (_Float16)(acc[mi][ni][j] + bv);
          if (part < 2) {
            const size_t idx = ((((size_t)(bh * 64 + (s >> 4)) * 3 + (d >> 5)) * 64
                                + ((d & 31) >> 3) * 16 + (s & 15)) << 3) + (d & 7);
            if (part == 0) Qo[idx] = v; else Ko[idx] = v;
          } else {
            const size_t idx = ((((size_t)(bh * 6 + (d >> 4)) * 32 + (s >> 5)) * 64
                                + ((s & 31) >> 3) * 16 + (d & 15)) << 3) + (s & 7);
            Vto[idx] = v;
          }
        }
      } else {
        const float bv = b0[col];
#pragma unroll
        for (int j = 0; j < 4; ++j) {
          const int row = rbase + j;
          Co[(size_t)row * 768 + col] = acc[mi][ni][j] + bv;
        }
      }
    }
  }
}

// ---------------- fused attention v8: 32 q-rows/block, K/V regs reused 2x ----------------
// 8 waves/block; wave w owns k-slice [w*128, w*128+128) for TWO 16-row q-tiles
// (A then B), holding kf[8][3] + vf[6][4] in registers across both -> K/V L2
// traffic halved vs v7. V loads issued before the lsum barrier to hide latency.
__global__ __launch_bounds__(512, 2) void attn(const _Float16* __restrict__ swzQ,
                                               const _Float16* __restrict__ swzK,
                                               const _Float16* __restrict__ swzV,
                                               float* __restrict__ probs,
                                               _Float16* __restrict__ ctx) {
  __shared__ __align__(16) float Pf[8][16][132];  // per-wave f32 P tile / ctx-partial
  __shared__ float lsb[8][2][16];
  const int tid = threadIdx.x, w = tid >> 6, l = tid & 63;
  const int lr = l & 15, lk = l >> 4;
  const int id = blockIdx.x;
  const int lid = (id & 7) * 512 + (id >> 3);   // XCD-chunked (4096 = 8*512)
  const int bh = lid >> 5, qt2 = lid & 31;
  const int q0 = qt2 * 32;
  const float SC = 0.10206207261596577f * 1.4426950408889634f;  // (1/sqrt(96)) * log2(e)
  const int b = bh >> 3, h = bh & 7;

  // ---- hoisted coalesced fragment loads ----
  const half8* qbA = (const half8*)swzQ + (size_t)(bh * 64 + qt2 * 2) * 192;
  const half8* kb  = (const half8*)swzK + (size_t)(bh * 64 + w * 8) * 192;
  const half8* vb0 = (const half8*)swzV + (size_t)bh * 12288;
  half8 bqA[3], bqB[3];
#pragma unroll
  for (int kk = 0; kk < 3; ++kk) { bqA[kk] = qbA[kk * 64 + l]; bqB[kk] = qbA[192 + kk * 64 + l]; }
  half8 kf[8][3];
#pragma unroll
  for (int ct = 0; ct < 8; ++ct)
#pragma unroll
    for (int kk = 0; kk < 3; ++kk) kf[ct][kk] = kb[(ct * 3 + kk) * 64 + l];

  // ---- QK^T for both q-tiles (kf reused) ----
  f32x4 sA[8], sB[8];
#pragma unroll
  for (int ct = 0; ct < 8; ++ct) {
    f32x4 aA = {0.f, 0.f, 0.f, 0.f}, aB = {0.f, 0.f, 0.f, 0.f};
#pragma unroll
    for (int kk = 0; kk < 3; ++kk) {
      aA = __builtin_amdgcn_mfma_f32_16x16x32_f16(kf[ct][kk], bqA[kk], aA, 0, 0, 0);
      aB = __builtin_amdgcn_mfma_f32_16x16x32_f16(kf[ct][kk], bqB[kk], aB, 0, 0, 0);
    }
    sA[ct] = aA; sB[ct] = aB;
  }

  // ---- exp + per-lane partial sums ----
  float psA = 0.f, psB = 0.f;
#pragma unroll
  for (int ct = 0; ct < 8; ++ct)
#pragma unroll
    for (int j = 0; j < 4; ++j) {
      const float eA = __builtin_amdgcn_exp2f(sA[ct][j] * SC);
      const float eB = __builtin_amdgcn_exp2f(sB[ct][j] * SC);
      sA[ct][j] = eA; psA += eA;
      sB[ct][j] = eB; psB += eB;
    }
  psA += __shfl_xor(psA, 16); psA += __shfl_xor(psA, 32);
  psB += __shfl_xor(psB, 16); psB += __shfl_xor(psB, 32);
  if (lk == 0) { lsb[w][0][lr] = psA; lsb[w][1][lr] = psB; }

  // ---- V loads issued BEFORE the barrier (latency hides under it) ----
  half8 vf[6][4];
#pragma unroll
  for (int dt = 0; dt < 6; ++dt)
#pragma unroll
    for (int kk = 0; kk < 4; ++kk) vf[dt][kk] = vb0[(dt * 32 + w * 4 + kk) * 64 + l];

  __syncthreads();                                   // B1
  float ltA = 0.f, ltB = 0.f;
#pragma unroll
  for (int ww = 0; ww < 8; ++ww) { ltA += lsb[ww][0][lr]; ltB += lsb[ww][1][lr]; }
  const float invlA = 1.f / ltA, invlB = 1.f / ltB;

  const int qh = l >> 5, c4 = (l & 31) * 4;
  float* cbw = (float*)&Pf[w][0][0];                 // [16][100] view for ctx partials
  const int rq = tid >> 5;                           // 0..15 (ctx reduce row)
  const int rd0 = (tid & 31) * 3;                    // 0..93

  // ================= phase A =================
#pragma unroll
  for (int ct = 0; ct < 8; ++ct) {
    f32x4 p4;
#pragma unroll
    for (int j = 0; j < 4; ++j) p4[j] = sA[ct][j] * invlA;
    *(f32x4*)&Pf[w][lr][ct * 16 + lk * 4] = p4;
  }
  {
    float* pbase = probs + ((size_t)bh << 20) + (size_t)q0 * 1024 + w * 128;
#pragma unroll
    for (int r2 = 0; r2 < 8; ++r2) {
      const int q = r2 * 2 + qh;
      f32x4 v = *(const f32x4*)&Pf[w][q][c4];
      __builtin_nontemporal_store(v, (f32x4*)(pbase + (size_t)q * 1024 + c4));
    }
  }
  f32x4 cacc[6] = {};
#pragma unroll
  for (int kk = 0; kk < 4; ++kk) {
    f32x4 a0 = *(const f32x4*)&Pf[w][lr][kk * 32 + lk * 8];
    f32x4 a1 = *(const f32x4*)&Pf[w][lr][kk * 32 + lk * 8 + 4];
    half8 pa;
#pragma unroll
    for (int e = 0; e < 4; ++e) { pa[e] = (_Float16)a0[e]; pa[4 + e] = (_Float16)a1[e]; }
#pragma unroll
    for (int dt = 0; dt < 6; ++dt)
      cacc[dt] = __builtin_amdgcn_mfma_f32_16x16x32_f16(pa, vf[dt][kk], cacc[dt], 0, 0, 0);
  }
#pragma unroll
  for (int dt = 0; dt < 6; ++dt)
#pragma unroll
    for (int j = 0; j < 4; ++j)
      cbw[(lk * 4 + j) * 100 + dt * 16 + lr] = cacc[dt][j];
  __syncthreads();                                   // B2
  {
    _Float16* cg = ctx + ((size_t)(b * 1024 + q0 + rq)) * 768 + h * 96 + rd0;
#pragma unroll
    for (int e = 0; e < 3; ++e) {
      float v = 0.f;
#pragma unroll
      for (int ww = 0; ww < 8; ++ww) v += ((const float*)&Pf[ww][0][0])[rq * 100 + rd0 + e];
      cg[e] = (_Float16)v;
    }
  }
  __syncthreads();                                   // B3

  // ================= phase B (vf reused) =================
#pragma unroll
  for (int ct = 0; ct < 8; ++ct) {
    f32x4 p4;
#pragma unroll
    for (int j = 0; j < 4; ++j) p4[j] = sB[ct][j] * invlB;
    *(f32x4*)&Pf[w][lr][ct * 16 + lk * 4] = p4;
  }
  {
    float* pbase = probs + ((size_t)bh << 20) + (size_t)(q0 + 16) * 1024 + w * 128;
#pragma unroll
    for (int r2 = 0; r2 < 8; ++r2) {
      const int q = r2 * 2 + qh;
      f32x4 v = *(const f32x4*)&Pf[w][q][c4];
      __builtin_nontemporal_store(v, (f32x4*)(pbase + (size_t)q * 1024 + c4));
    }
  }
#pragma unroll
  for (int dt = 0; dt < 6; ++dt) cacc[dt] = f32x4{0.f, 0.f, 0.f, 0.f};
#pragma unroll
  for (int kk = 0; kk < 4; ++kk) {
    f32x4 a0 = *(const f32x4*)&Pf[w][lr][kk * 32 + lk * 8];
    f32x4 a1 = *(const f32x4*)&Pf[w][lr][kk * 32 + lk * 8 + 4];
    half8 pa;
#pragma unroll
    for (int e = 0; e < 4; ++e) { pa[e] = (_Float16)a0[e]; pa[4 + e] = (_Float16)a1[e]; }
#pragma unroll
    for (int dt = 0; dt < 6; ++dt)
      cacc[dt] = __builtin_amdgcn_mfma_f32_16x16x32_f16(pa, vf[dt][kk], cacc[dt], 0, 0, 0);
  }
#pragma unroll
  for (int dt = 0; dt < 6; ++dt)
#pragma unroll
    for (int j = 0; j < 4; ++j)
      cbw[(lk * 4 + j) * 100 + dt * 16 + lr] = cacc[dt][j];
  __syncthreads();                                   // B4
  {
    _Float16* cg = ctx + ((size_t)(b * 1024 + q0 + 16 + rq)) * 768 + h * 96 + rd0;
#pragma unroll
    for (int e = 0; e < 3; ++e) {
      float v = 0.f;
#pragma unroll
      for (int ww = 0; ww < 8; ++ww) v += ((const float*)&Pf[ww][0][0])[rq * 100 + rd0 + e];
      cg[e] = (_Float16)v;
    }
  }
}

extern "C" void kernel_launch(void* const* d_in, const int* in_sizes, int n_in,
                              void* d_out, int out_size, void* d_ws, size_t ws_size,
                              hipStream_t stream) {
  (void)in_sizes; (void)n_in; (void)out_size; (void)ws_size;
  const float* X  = (const float*)d_in[0];
  const float* Wq = (const float*)d_in[1];
  const float* bq = (const float*)d_in[2];
  const float* Wk = (const float*)d_in[3];
  const float* bk = (const float*)d_in[4];
  const float* Wv = (const float*)d_in[5];
  const float* bv = (const float*)d_in[6];
  const float* Wo = (const float*)d_in[7];
  const float* bo = (const float*)d_in[8];

  char* ws = (char*)d_ws;
  _Float16* Xh    = (_Float16*)(ws + 0);          // 16384x768 fp16      (25165824 B)
  _Float16* Wqkvt = (_Float16*)(ws + 25165824);   // 2304x768 fp16       ( 3538944 B)
  _Float16* Wot   = (_Float16*)(ws + 28704768);   // 768x768 fp16        ( 1179648 B)
  _Float16* Qh    = (_Float16*)(ws + 29884416);   // swzQ                (25165824 B)
  _Float16* Kh    = (_Float16*)(ws + 55050240);   // swzK                (25165824 B)
  _Float16* Vth   = (_Float16*)(ws + 80216064);   // swzV                (25165824 B)
  _Float16* Ctx   = (_Float16*)(ws + 105381888);  // [16384][768]        (25165824 B)

  float* out   = (float*)d_out;
  float* probs = out + 12582912;                  // [16][8][1024][1024]

  cvt_x<<<dim3(6144), dim3(256), 0, stream>>>(X, Xh);
  cvt_w<<<dim3(9216), dim3(256), 0, stream>>>(Wq, Wk, Wv, Wo, Wqkvt, Wot);
  gemm_f16<0><<<dim3(18, 128), dim3(256), 0, stream>>>(Xh, Wqkvt, bq, bk, bv, Qh, Kh, Vth, nullptr);
  attn<<<dim3(4096), dim3(512), 0, stream>>>(Qh, Kh, Vth, probs, Ctx);
  gemm_f16<1><<<dim3(6, 128), dim3(256), 0, stream>>>(Ctx, Wot, bo, bo, bo, nullptr, nullptr, nullptr, out);
}